// Round 19
// baseline (70.851 us; speedup 1.0000x reference)
//
#include <hip/hip_runtime.h>
#include <hip/hip_bf16.h>

#define K1N 10
#define K2N 10
#define MMN 50

typedef __attribute__((ext_vector_type(8))) short short8;
typedef __attribute__((ext_vector_type(4))) float f32x4;
typedef __attribute__((ext_vector_type(4))) unsigned short us16x4;

__device__ __forceinline__ float fast_tanh(float x) {
  x = fminf(fmaxf(x, -15.f), 15.f);
  float e2 = __expf(2.f * x);
  return (e2 - 1.f) * __builtin_amdgcn_rcpf(e2 + 1.f);
}

// reference's _avg_on_real_neighbor weight (exact f32 semantics)
__device__ __forceinline__ float nb_w(float cnt) {
  float w = 1.0f / (cnt + 1e-8f);
  return (w >= 1e8f) ? 0.f : w;
}

// f32 -> bf16 via native cast (v_cvt_pk_bf16_f32); exact bf16 -> f32
__device__ __forceinline__ unsigned short f2bf(float x) {
  __hip_bfloat16 b = __float2bfloat16(x);
  return __builtin_bit_cast(unsigned short, b);
}
__device__ __forceinline__ float bf2f(unsigned short s) {
  return __builtin_bit_cast(float, ((unsigned)s) << 16);
}

__device__ __forceinline__ void fma4(float& y, float4 w, float4 x) {
  y = fmaf(w.x, x.x, y);
  y = fmaf(w.y, x.y, y);
  y = fmaf(w.z, x.z, y);
  y = fmaf(w.w, x.w, y);
}

#define MFMA16(A, B, C) __builtin_amdgcn_mfma_f32_16x16x32_bf16(A, B, C, 0, 0, 0)

// one phase-1 k-chunk, QUAD-ROW gather + MQ interleaved usu chunks.
// The usu loads are fully independent of the dise/symp chain -> they fill the
// memory pipe during this step's convert/MFMA phases (coda hidden under k-loop).
template <int KQ, int MQ>
__device__ __forceinline__ void p1_step(
    int kbase, int m0, int b0w, int lane, int grp, int c16, int r15, int g, int bpi,
    int4 i4,
    const float* __restrict__ symp, const float* __restrict__ dise,
    int sd, const int (&uie)[4], f32x4 (&su4)[4],
    const unsigned short* __restrict__ Wl,
    unsigned short* xw, float (&s1sum)[4]) {
  int idxa[4] = {i4.x, i4.y, i4.z, i4.w};

  f32x4 esv[KQ], acc[KQ];
  int c2[KQ];
  int sxv[KQ];
#pragma unroll
  for (int kq = 0; kq < KQ; ++kq)
    sxv[kq] = __builtin_amdgcn_ds_bpermute(bpi + ((kbase + kq) << 2), sd);
#pragma unroll
  for (int kq = 0; kq < KQ; ++kq)
    esv[kq] = *reinterpret_cast<const f32x4*>(symp + (sxv[kq] << 6) + (c16 << 2));

#pragma unroll
  for (int kq = 0; kq < KQ; ++kq) {
    int iv[K2N];
#pragma unroll
    for (int m = 0; m < K2N; ++m) {
      const int f = kq * K2N + m;
      iv[m] = __builtin_amdgcn_ds_bpermute(bpi + ((f >> 2) << 2), idxa[f & 3]);
    }
    f32x4 rb[K2N];
#pragma unroll
    for (int m = 0; m < K2N; ++m)
      rb[m] = *reinterpret_cast<const f32x4*>(dise + (iv[m] << 6) + (c16 << 2));  // row 0 = 0
    int cc = 0;
#pragma unroll
    for (int m = 0; m < K2N; ++m) cc += (iv[m] != 0);
    c2[kq] = cc;
    f32x4 s01 = rb[0] + rb[1];
    f32x4 s23 = rb[2] + rb[3];
    f32x4 s45 = rb[4] + rb[5];
    f32x4 s67 = rb[6] + rb[7];
    f32x4 s89 = rb[8] + rb[9];
    acc[kq] = ((s01 + s23) + (s45 + s67)) + s89;
  }

  // interleaved usu chunks: independent loads, hide under convert/MFMA below
#pragma unroll
  for (int mm = 0; mm < MQ; ++mm) {
#pragma unroll
    for (int e = 0; e < 4; ++e) {
      int idx = __shfl(uie[e], (m0 + (mm << 2)) + grp, 64);
      su4[e] += *(const f32x4*)(symp + (idx << 6) + (c16 << 2));  // symp row 0 = 0
    }
  }

#pragma unroll
  for (int kq = 0; kq < KQ; ++kq) {
    float w2 = (c2[kq] == 0) ? 0.f : __builtin_amdgcn_rcpf((float)c2[kq] + 1e-8f);
    f32x4 ad = acc[kq] * w2;
    f32x4 t1 = esv[kq] + ad;
    f32x4 t2 = esv[kq] * ad;
    const int u = (grp << 2) | kq;
    const int off = u * 64 + (((c16 >> 1) ^ (u & 7)) << 3) + ((c16 & 1) << 2);
    us16x4 h1, l1, h2;
#pragma unroll
    for (int c = 0; c < 4; ++c) {
      unsigned short hh = f2bf(t1[c]);
      h1[c] = hh;
      l1[c] = f2bf(t1[c] - bf2f(hh));
      h2[c] = f2bf(t2[c]);
    }
    *reinterpret_cast<us16x4*>(xw + off) = h1;
    *reinterpret_cast<us16x4*>(xw + 1024 + off) = l1;
    *reinterpret_cast<us16x4*>(xw + 2048 + off) = h2;
  }

  f32x4 acc4[4];
#pragma unroll
  for (int nt = 0; nt < 4; ++nt) acc4[nt] = (f32x4){0.f, 0.f, 0.f, 0.f};
#pragma unroll
  for (int ks = 0; ks < 2; ++ks) {
    const int aoff = r15 * 64 + (((4 * ks + g) ^ (r15 & 7)) << 3);
    short8 a1h = *(const short8*)(xw + aoff);
    short8 a1l = *(const short8*)(xw + 1024 + aoff);
    short8 a2h = *(const short8*)(xw + 2048 + aoff);
#pragma unroll
    for (int nt = 0; nt < 4; ++nt) {
      const int wb = (nt * 16 + r15) * 64 + (((4 * ks + g) ^ (r15 & 7)) << 3);
      short8 w21h = *(const short8*)(Wl + 0 * 4096 + wb);
      short8 w21l = *(const short8*)(Wl + 1 * 4096 + wb);
      short8 w22h = *(const short8*)(Wl + 2 * 4096 + wb);
      acc4[nt] = MFMA16(a1h, w21h, acc4[nt]);
      acc4[nt] = MFMA16(a1l, w21h, acc4[nt]);
      acc4[nt] = MFMA16(a1h, w21l, acc4[nt]);
      acc4[nt] = MFMA16(a2h, w22h, acc4[nt]);
    }
  }
#pragma unroll
  for (int rr = 0; rr < KQ; ++rr) {
    float ta[4], ss = 0.f;
#pragma unroll
    for (int nt = 0; nt < 4; ++nt) {
      ta[nt] = fast_tanh(acc4[nt][rr]);
      ss = fmaf(ta[nt], ta[nt], ss);
    }
    ss += __shfl_xor(ss, 1, 64); ss += __shfl_xor(ss, 2, 64);
    ss += __shfl_xor(ss, 4, 64); ss += __shfl_xor(ss, 8, 64);
    float inv = __builtin_amdgcn_rcpf(fmaxf(sqrtf(ss), 1e-12f));
#pragma unroll
    for (int nt = 0; nt < 4; ++nt) s1sum[nt] = fmaf(ta[nt], inv, s1sum[nt]);
  }
}

// ====== FULLY FUSED, W-in-LDS, usu coda interleaved into k-loop ======
__global__ __launch_bounds__(512, 2) void hgnn_fused(
    const int* __restrict__ dsd1, const int* __restrict__ dsd2,
    const int* __restrict__ usu1, const int* __restrict__ label,
    const float* __restrict__ symp, const float* __restrict__ dise,
    const float* __restrict__ W21, const float* __restrict__ W22,
    const float* __restrict__ W11, const float* __restrict__ W12,
    const float* __restrict__ Wu, float* __restrict__ out) {
  __shared__ __align__(16) unsigned char smem[73728];
  unsigned short* Wlp = (unsigned short*)smem;             // 24 KB: {w21h, w21l, w22h}
  unsigned short* XsB = (unsigned short*)(smem + 24576);   // 48 KB, 6 KB/wave

  const int tid = threadIdx.x;
  const int lane = tid & 63;
  const int wv = __builtin_amdgcn_readfirstlane(tid >> 6);
  const int g = lane >> 4, r15 = lane & 15;
  const int grp = g, c16 = r15;
  const int bpi = (lane & 48) << 2;

  const int b0w = blockIdx.x * 32 + wv * 4;

  // ---- EARLY index preloads: all 3 steps' dsd2 quads + dsd1 + usu indices ----
  const int* d2base = dsd2 + (b0w + grp) * (K1N * K2N);
  int4 i4a = {0, 0, 0, 0}, i4b = {0, 0, 0, 0}, i4c = {0, 0, 0, 0};
  if (c16 < 10) {
    i4a = *reinterpret_cast<const int4*>(d2base + (c16 << 2));
    i4b = *reinterpret_cast<const int4*>(d2base + 40 + (c16 << 2));
  }
  if (c16 < 5) i4c = *reinterpret_cast<const int4*>(d2base + 80 + (c16 << 2));
  int sd = 0;
  if (c16 < K1N) sd = dsd1[(b0w + grp) * K1N + c16];
  int uie[4];
#pragma unroll
  for (int e = 0; e < 4; ++e) {
    int v = 0;
    if (lane < MMN) v = usu1[(b0w + e) * MMN + lane];
    uie[e] = v;
  }

  // stage 3 W planes {w21h, w21l, w22h} bf16 swizzled: 1536 chunks, 3/thread
#pragma unroll
  for (int i = 0; i < 3; ++i) {
    int c = tid + (i << 9);
    int pl = c >> 9, rc = c & 511;
    int row = rc >> 3, ch = rc & 7;
    const float* src = ((pl == 2) ? W22 : W21) + row * 64 + ch * 8;
    const bool lo = (pl == 1);
    short8 v;
#pragma unroll
    for (int j = 0; j < 8; ++j) {
      float w = src[j];
      unsigned short h = f2bf(w);
      v[j] = (short)(lo ? f2bf(w - bf2f(h)) : h);
    }
    *reinterpret_cast<short8*>(&Wlp[pl * 4096 + row * 64 + ((ch ^ (row & 7)) << 3)]) = v;
  }
  __syncthreads();

  unsigned short* xw = XsB + wv * 3072;
  float s1sum[4] = {0.f, 0.f, 0.f, 0.f};

  unsigned long long ball = __ballot((c16 < K1N) && (sd != 0));
  float c1f = (float)__popcll(ball & (1023ull << (grp << 4)));

  // usu accumulators (persist across steps; accumulation order identical to r18)
  f32x4 su4[4];
  float cnt4[4];
#pragma unroll
  for (int e = 0; e < 4; ++e) {
    cnt4[e] = (float)__popcll(__ballot(uie[e] != 0));
    su4[e] = (f32x4){0.f, 0.f, 0.f, 0.f};
  }

  p1_step<4, 5>(0, 0, b0w, lane, grp, c16, r15, g, bpi, i4a, symp, dise, sd, uie, su4, Wlp, xw, s1sum);
  p1_step<4, 5>(4, 20, b0w, lane, grp, c16, r15, g, bpi, i4b, symp, dise, sd, uie, su4, Wlp, xw, s1sum);
  p1_step<2, 2>(8, 40, b0w, lane, grp, c16, r15, g, bpi, i4c, symp, dise, sd, uie, su4, Wlp, xw, s1sum);

  // s1 for elem g stays in registers (cols nt*16 + r15)
  float w1 = nb_w(c1f);
  float s1f[4];
#pragma unroll
  for (int nt = 0; nt < 4; ++nt) s1f[nt] = s1sum[nt] * w1;

  // ---- usu tail (m=48,49) + cross-group reduce + scale ----
  const int d4 = (lane & 15) << 2;
#pragma unroll
  for (int e = 0; e < 4; ++e) {
    int idx = __shfl(uie[e], 48 + grp, 64);
    if (grp < 2) su4[e] += *(const f32x4*)(symp + (idx << 6) + d4);
  }
#pragma unroll
  for (int e = 0; e < 4; ++e) {
#pragma unroll
    for (int c = 0; c < 4; ++c) {
      su4[e][c] += __shfl_xor(su4[e][c], 16, 64);
      su4[e][c] += __shfl_xor(su4[e][c], 32, 64);
    }
    su4[e] = su4[e] * nb_w(cnt4[e]);
  }

  // ================= final coda: overlay LDS, 3 matvecs + dot =================
  __syncthreads();  // everyone done with Wl/Xs before overwrite

  float4* lwf4 = (float4*)smem;               // 48 KB: W11,W12,Wu f32 swizzled
  float* xb = (float*)(smem + 49152);         // 24 KB: [8 waves][4 elems][3 planes][64]
  float* xbw = xb + wv * (4 * 3 * 64);

  // stage 3 f32 W matrices: 3072 float4 chunks, 6/thread
#pragma unroll
  for (int i = 0; i < 6; ++i) {
    int c = tid + (i << 9);
    int mt = c >> 10, rc = c & 1023;
    int e = rc >> 4, q = rc & 15;
    const float4* srcp = reinterpret_cast<const float4*>(mt == 0 ? W11 : (mt == 1 ? W12 : Wu));
    lwf4[(mt << 10) | (e << 4) | (q ^ (e & 7))] = srcp[rc];
  }
  // scatter s1 (elem g) and mu (all elems) into xb
#pragma unroll
  for (int nt = 0; nt < 4; ++nt) xbw[(g * 3 + 0) * 64 + nt * 16 + r15] = s1f[nt];
  if (lane < 16) {
#pragma unroll
    for (int e = 0; e < 4; ++e)
      *reinterpret_cast<f32x4*>(&xbw[(e * 3 + 2) * 64 + d4]) = su4[e];
  }
  __syncthreads();  // staged W visible; own-wave xb writes DS-pipe-ordered

  // x1 = s1 + t, x2 = s1 * t (lane = d)
#pragma unroll
  for (int bi = 0; bi < 4; ++bi) {
    int lb = label[b0w + bi];
    float t = dise[(lb << 6) | lane];
    float s1v = xbw[(bi * 3 + 0) * 64 + lane];
    xbw[(bi * 3 + 0) * 64 + lane] = s1v + t;
    xbw[(bi * 3 + 1) * 64 + lane] = s1v * t;
  }

  // crossbar matvec (proven round-3 final): lane = output col e
  float y1[4] = {0.f, 0.f, 0.f, 0.f};
  float y2[4] = {0.f, 0.f, 0.f, 0.f};
  const int swz = lane & 7;
#pragma unroll 4
  for (int q = 0; q < 16; ++q) {
    float4 wa = lwf4[(0 << 10) | (lane << 4) | (q ^ swz)];
    float4 wb = lwf4[(1 << 10) | (lane << 4) | (q ^ swz)];
    float4 wc = lwf4[(2 << 10) | (lane << 4) | (q ^ swz)];
#pragma unroll
    for (int bi = 0; bi < 4; ++bi) {
      float4 xv1 = *reinterpret_cast<const float4*>(&xbw[(bi * 3 + 0) * 64 + (q << 2)]);
      float4 xv2 = *reinterpret_cast<const float4*>(&xbw[(bi * 3 + 1) * 64 + (q << 2)]);
      float4 xv3 = *reinterpret_cast<const float4*>(&xbw[(bi * 3 + 2) * 64 + (q << 2)]);
      fma4(y1[bi], wa, xv1);
      fma4(y1[bi], wb, xv2);
      fma4(y2[bi], wc, xv3);
    }
  }
#pragma unroll
  for (int bi = 0; bi < 4; ++bi) {
    float p = fast_tanh(y1[bi]) * fast_tanh(y2[bi]);
#pragma unroll
    for (int off = 32; off; off >>= 1) p += __shfl_xor(p, off, 64);
    if (lane == 0) out[b0w + bi] = p;
  }
}

extern "C" void kernel_launch(void* const* d_in, const int* in_sizes, int n_in,
                              void* d_out, int out_size, void* d_ws, size_t ws_size,
                              hipStream_t stream) {
  const int* dsd1 = (const int*)d_in[0];
  const int* dsd2 = (const int*)d_in[1];
  const int* usu1 = (const int*)d_in[2];
  const int* label = (const int*)d_in[3];
  const float* symp = (const float*)d_in[4];
  const float* dise = (const float*)d_in[5];
  const float* Wu = (const float*)d_in[6];
  const float* W21 = (const float*)d_in[7];
  const float* W22 = (const float*)d_in[8];
  const float* W11 = (const float*)d_in[9];
  const float* W12 = (const float*)d_in[10];
  float* out = (float*)d_out;

  const int B = in_sizes[3];
  hipLaunchKernelGGL(hgnn_fused, dim3(B / 32), dim3(512), 0, stream,
                     dsd1, dsd2, usu1, label, symp, dise, W21, W22, W11, W12, Wu, out);
}

// Round 20
// 68.368 us; speedup vs baseline: 1.0363x; 1.0363x over previous
//
#include <hip/hip_runtime.h>
#include <hip/hip_bf16.h>

#define K1N 10
#define K2N 10
#define MMN 50

typedef __attribute__((ext_vector_type(8))) short short8;
typedef __attribute__((ext_vector_type(4))) float f32x4;
typedef __attribute__((ext_vector_type(4))) unsigned short us16x4;

__device__ __forceinline__ float fast_tanh(float x) {
  x = fminf(fmaxf(x, -15.f), 15.f);
  float e2 = __expf(2.f * x);
  return (e2 - 1.f) * __builtin_amdgcn_rcpf(e2 + 1.f);
}

// reference's _avg_on_real_neighbor weight (exact f32 semantics)
__device__ __forceinline__ float nb_w(float cnt) {
  float w = 1.0f / (cnt + 1e-8f);
  return (w >= 1e8f) ? 0.f : w;
}

// f32 -> bf16 via native cast (v_cvt_pk_bf16_f32); exact bf16 -> f32
__device__ __forceinline__ unsigned short f2bf(float x) {
  __hip_bfloat16 b = __float2bfloat16(x);
  return __builtin_bit_cast(unsigned short, b);
}
__device__ __forceinline__ float bf2f(unsigned short s) {
  return __builtin_bit_cast(float, ((unsigned)s) << 16);
}

__device__ __forceinline__ void fma4(float& y, float4 w, float4 x) {
  y = fmaf(w.x, x.x, y);
  y = fmaf(w.y, x.y, y);
  y = fmaf(w.z, x.z, y);
  y = fmaf(w.w, x.w, y);
}

#define MFMA16(A, B, C) __builtin_amdgcn_mfma_f32_16x16x32_bf16(A, B, C, 0, 0, 0)

// one phase-1 k-chunk, QUAD-ROW gather, BATCHED per-kq: all 10 bpermutes, then all
// 10 row loads into a register buffer, then tree-reduce (dep depth 4 vs 10 serial
// bpermute->load->add round-trips). W in LDS; 3 X planes {t1h,t1l,t2h}.
template <int KQ>
__device__ __forceinline__ void p1_step(
    int kbase, int b0w, int lane, int grp, int c16, int r15, int g, int bpi,
    int4 i4,
    const float* __restrict__ symp, const float* __restrict__ dise,
    int sd, const unsigned short* __restrict__ Wl,
    unsigned short* xw, float (&s1sum)[4]) {
  int idxa[4] = {i4.x, i4.y, i4.z, i4.w};

  f32x4 esv[KQ], acc[KQ];
  int c2[KQ];
  int sxv[KQ];
#pragma unroll
  for (int kq = 0; kq < KQ; ++kq)
    sxv[kq] = __builtin_amdgcn_ds_bpermute(bpi + ((kbase + kq) << 2), sd);
#pragma unroll
  for (int kq = 0; kq < KQ; ++kq)
    esv[kq] = *reinterpret_cast<const f32x4*>(symp + (sxv[kq] << 6) + (c16 << 2));

#pragma unroll
  for (int kq = 0; kq < KQ; ++kq) {
    // batch 1: all 10 index broadcasts (independent LDS ops)
    int iv[K2N];
#pragma unroll
    for (int m = 0; m < K2N; ++m) {
      const int f = kq * K2N + m;
      iv[m] = __builtin_amdgcn_ds_bpermute(bpi + ((f >> 2) << 2), idxa[f & 3]);
    }
    // batch 2: all 10 row loads into register buffer (10 in flight)
    f32x4 rb[K2N];
#pragma unroll
    for (int m = 0; m < K2N; ++m)
      rb[m] = *reinterpret_cast<const f32x4*>(dise + (iv[m] << 6) + (c16 << 2));  // row 0 = 0
    int cc = 0;
#pragma unroll
    for (int m = 0; m < K2N; ++m) cc += (iv[m] != 0);
    c2[kq] = cc;
    // tree reduce: dependency depth 4
    f32x4 s01 = rb[0] + rb[1];
    f32x4 s23 = rb[2] + rb[3];
    f32x4 s45 = rb[4] + rb[5];
    f32x4 s67 = rb[6] + rb[7];
    f32x4 s89 = rb[8] + rb[9];
    acc[kq] = ((s01 + s23) + (s45 + s67)) + s89;
  }

#pragma unroll
  for (int kq = 0; kq < KQ; ++kq) {
    float w2 = (c2[kq] == 0) ? 0.f : __builtin_amdgcn_rcpf((float)c2[kq] + 1e-8f);
    f32x4 ad = acc[kq] * w2;
    f32x4 t1 = esv[kq] + ad;
    f32x4 t2 = esv[kq] * ad;
    const int u = (grp << 2) | kq;
    const int off = u * 64 + (((c16 >> 1) ^ (u & 7)) << 3) + ((c16 & 1) << 2);
    us16x4 h1, l1, h2;
#pragma unroll
    for (int c = 0; c < 4; ++c) {
      unsigned short hh = f2bf(t1[c]);
      h1[c] = hh;
      l1[c] = f2bf(t1[c] - bf2f(hh));
      h2[c] = f2bf(t2[c]);
    }
    *reinterpret_cast<us16x4*>(xw + off) = h1;
    *reinterpret_cast<us16x4*>(xw + 1024 + off) = l1;
    *reinterpret_cast<us16x4*>(xw + 2048 + off) = h2;
  }

  f32x4 acc4[4];
#pragma unroll
  for (int nt = 0; nt < 4; ++nt) acc4[nt] = (f32x4){0.f, 0.f, 0.f, 0.f};
#pragma unroll
  for (int ks = 0; ks < 2; ++ks) {
    const int aoff = r15 * 64 + (((4 * ks + g) ^ (r15 & 7)) << 3);
    short8 a1h = *(const short8*)(xw + aoff);
    short8 a1l = *(const short8*)(xw + 1024 + aoff);
    short8 a2h = *(const short8*)(xw + 2048 + aoff);
#pragma unroll
    for (int nt = 0; nt < 4; ++nt) {
      const int wb = (nt * 16 + r15) * 64 + (((4 * ks + g) ^ (r15 & 7)) << 3);
      short8 w21h = *(const short8*)(Wl + 0 * 4096 + wb);
      short8 w21l = *(const short8*)(Wl + 1 * 4096 + wb);
      short8 w22h = *(const short8*)(Wl + 2 * 4096 + wb);
      acc4[nt] = MFMA16(a1h, w21h, acc4[nt]);
      acc4[nt] = MFMA16(a1l, w21h, acc4[nt]);
      acc4[nt] = MFMA16(a1h, w21l, acc4[nt]);
      acc4[nt] = MFMA16(a2h, w22h, acc4[nt]);
    }
  }
#pragma unroll
  for (int rr = 0; rr < KQ; ++rr) {
    float ta[4], ss = 0.f;
#pragma unroll
    for (int nt = 0; nt < 4; ++nt) {
      ta[nt] = fast_tanh(acc4[nt][rr]);
      ss = fmaf(ta[nt], ta[nt], ss);
    }
    ss += __shfl_xor(ss, 1, 64); ss += __shfl_xor(ss, 2, 64);
    ss += __shfl_xor(ss, 4, 64); ss += __shfl_xor(ss, 8, 64);
    float inv = __builtin_amdgcn_rcpf(fmaxf(sqrtf(ss), 1e-12f));
#pragma unroll
    for (int nt = 0; nt < 4; ++nt) s1sum[nt] = fmaf(ta[nt], inv, s1sum[nt]);
  }
}

// ====== FULLY FUSED, W-in-LDS, batched gather pipeline (round-18 best) ======
__global__ __launch_bounds__(512, 2) void hgnn_fused(
    const int* __restrict__ dsd1, const int* __restrict__ dsd2,
    const int* __restrict__ usu1, const int* __restrict__ label,
    const float* __restrict__ symp, const float* __restrict__ dise,
    const float* __restrict__ W21, const float* __restrict__ W22,
    const float* __restrict__ W11, const float* __restrict__ W12,
    const float* __restrict__ Wu, float* __restrict__ out) {
  __shared__ __align__(16) unsigned char smem[73728];
  unsigned short* Wlp = (unsigned short*)smem;             // 24 KB: {w21h, w21l, w22h}
  unsigned short* XsB = (unsigned short*)(smem + 24576);   // 48 KB, 6 KB/wave

  const int tid = threadIdx.x;
  const int lane = tid & 63;
  const int wv = __builtin_amdgcn_readfirstlane(tid >> 6);
  const int g = lane >> 4, r15 = lane & 15;
  const int grp = g, c16 = r15;
  const int bpi = (lane & 48) << 2;

  const int b0w = blockIdx.x * 32 + wv * 4;

  // ---- EARLY index preloads: all 3 steps' dsd2 quads + dsd1 + usu indices ----
  const int* d2base = dsd2 + (b0w + grp) * (K1N * K2N);
  int4 i4a = {0, 0, 0, 0}, i4b = {0, 0, 0, 0}, i4c = {0, 0, 0, 0};
  if (c16 < 10) {
    i4a = *reinterpret_cast<const int4*>(d2base + (c16 << 2));
    i4b = *reinterpret_cast<const int4*>(d2base + 40 + (c16 << 2));
  }
  if (c16 < 5) i4c = *reinterpret_cast<const int4*>(d2base + 80 + (c16 << 2));
  int sd = 0;
  if (c16 < K1N) sd = dsd1[(b0w + grp) * K1N + c16];
  int uie[4];
#pragma unroll
  for (int e = 0; e < 4; ++e) {
    int v = 0;
    if (lane < MMN) v = usu1[(b0w + e) * MMN + lane];
    uie[e] = v;
  }

  // stage 3 W planes {w21h, w21l, w22h} bf16 swizzled: 1536 chunks, 3/thread
#pragma unroll
  for (int i = 0; i < 3; ++i) {
    int c = tid + (i << 9);
    int pl = c >> 9, rc = c & 511;
    int row = rc >> 3, ch = rc & 7;
    const float* src = ((pl == 2) ? W22 : W21) + row * 64 + ch * 8;
    const bool lo = (pl == 1);
    short8 v;
#pragma unroll
    for (int j = 0; j < 8; ++j) {
      float w = src[j];
      unsigned short h = f2bf(w);
      v[j] = (short)(lo ? f2bf(w - bf2f(h)) : h);
    }
    *reinterpret_cast<short8*>(&Wlp[pl * 4096 + row * 64 + ((ch ^ (row & 7)) << 3)]) = v;
  }
  __syncthreads();

  unsigned short* xw = XsB + wv * 3072;
  float s1sum[4] = {0.f, 0.f, 0.f, 0.f};

  unsigned long long ball = __ballot((c16 < K1N) && (sd != 0));
  float c1f = (float)__popcll(ball & (1023ull << (grp << 4)));

  p1_step<4>(0, b0w, lane, grp, c16, r15, g, bpi, i4a, symp, dise, sd, Wlp, xw, s1sum);
  p1_step<4>(4, b0w, lane, grp, c16, r15, g, bpi, i4b, symp, dise, sd, Wlp, xw, s1sum);
  p1_step<2>(8, b0w, lane, grp, c16, r15, g, bpi, i4c, symp, dise, sd, Wlp, xw, s1sum);

  // s1 for elem g stays in registers (cols nt*16 + r15)
  float w1 = nb_w(c1f);
  float s1f[4];
#pragma unroll
  for (int nt = 0; nt < 4; ++nt) s1f[nt] = s1sum[nt] * w1;

  // ---- usu coda: quad-row gather, elem-interleaved (4 independent chains) ----
  const int d4 = (lane & 15) << 2;
  f32x4 su4[4];
  float cnt4[4];
#pragma unroll
  for (int e = 0; e < 4; ++e) {
    cnt4[e] = (float)__popcll(__ballot(uie[e] != 0));
    su4[e] = (f32x4){0.f, 0.f, 0.f, 0.f};
  }
#pragma unroll
  for (int m = 0; m < 48; m += 4) {
#pragma unroll
    for (int e = 0; e < 4; ++e) {
      int idx = __shfl(uie[e], m + grp, 64);
      su4[e] += *(const f32x4*)(symp + (idx << 6) + d4);  // symp row 0 is exactly zero
    }
  }
#pragma unroll
  for (int e = 0; e < 4; ++e) {
    int idx = __shfl(uie[e], 48 + grp, 64);
    if (grp < 2) su4[e] += *(const f32x4*)(symp + (idx << 6) + d4);
  }
#pragma unroll
  for (int e = 0; e < 4; ++e) {
#pragma unroll
    for (int c = 0; c < 4; ++c) {
      su4[e][c] += __shfl_xor(su4[e][c], 16, 64);
      su4[e][c] += __shfl_xor(su4[e][c], 32, 64);
    }
    su4[e] = su4[e] * nb_w(cnt4[e]);
  }

  // ================= final coda: overlay LDS, 3 matvecs + dot =================
  __syncthreads();  // everyone done with Wl/Xs before overwrite

  float4* lwf4 = (float4*)smem;               // 48 KB: W11,W12,Wu f32 swizzled
  float* xb = (float*)(smem + 49152);         // 24 KB: [8 waves][4 elems][3 planes][64]
  float* xbw = xb + wv * (4 * 3 * 64);

  // stage 3 f32 W matrices: 3072 float4 chunks, 6/thread
#pragma unroll
  for (int i = 0; i < 6; ++i) {
    int c = tid + (i << 9);
    int mt = c >> 10, rc = c & 1023;
    int e = rc >> 4, q = rc & 15;
    const float4* srcp = reinterpret_cast<const float4*>(mt == 0 ? W11 : (mt == 1 ? W12 : Wu));
    lwf4[(mt << 10) | (e << 4) | (q ^ (e & 7))] = srcp[rc];
  }
  // scatter s1 (elem g) and mu (all elems) into xb
#pragma unroll
  for (int nt = 0; nt < 4; ++nt) xbw[(g * 3 + 0) * 64 + nt * 16 + r15] = s1f[nt];
  if (lane < 16) {
#pragma unroll
    for (int e = 0; e < 4; ++e)
      *reinterpret_cast<f32x4*>(&xbw[(e * 3 + 2) * 64 + d4]) = su4[e];
  }
  __syncthreads();  // staged W visible; own-wave xb writes DS-pipe-ordered

  // x1 = s1 + t, x2 = s1 * t (lane = d)
#pragma unroll
  for (int bi = 0; bi < 4; ++bi) {
    int lb = label[b0w + bi];
    float t = dise[(lb << 6) | lane];
    float s1v = xbw[(bi * 3 + 0) * 64 + lane];
    xbw[(bi * 3 + 0) * 64 + lane] = s1v + t;
    xbw[(bi * 3 + 1) * 64 + lane] = s1v * t;
  }

  // crossbar matvec (proven round-3 final): lane = output col e
  float y1[4] = {0.f, 0.f, 0.f, 0.f};
  float y2[4] = {0.f, 0.f, 0.f, 0.f};
  const int swz = lane & 7;
#pragma unroll 4
  for (int q = 0; q < 16; ++q) {
    float4 wa = lwf4[(0 << 10) | (lane << 4) | (q ^ swz)];
    float4 wb = lwf4[(1 << 10) | (lane << 4) | (q ^ swz)];
    float4 wc = lwf4[(2 << 10) | (lane << 4) | (q ^ swz)];
#pragma unroll
    for (int bi = 0; bi < 4; ++bi) {
      float4 xv1 = *reinterpret_cast<const float4*>(&xbw[(bi * 3 + 0) * 64 + (q << 2)]);
      float4 xv2 = *reinterpret_cast<const float4*>(&xbw[(bi * 3 + 1) * 64 + (q << 2)]);
      float4 xv3 = *reinterpret_cast<const float4*>(&xbw[(bi * 3 + 2) * 64 + (q << 2)]);
      fma4(y1[bi], wa, xv1);
      fma4(y1[bi], wb, xv2);
      fma4(y2[bi], wc, xv3);
    }
  }
#pragma unroll
  for (int bi = 0; bi < 4; ++bi) {
    float p = fast_tanh(y1[bi]) * fast_tanh(y2[bi]);
#pragma unroll
    for (int off = 32; off; off >>= 1) p += __shfl_xor(p, off, 64);
    if (lane == 0) out[b0w + bi] = p;
  }
}

extern "C" void kernel_launch(void* const* d_in, const int* in_sizes, int n_in,
                              void* d_out, int out_size, void* d_ws, size_t ws_size,
                              hipStream_t stream) {
  const int* dsd1 = (const int*)d_in[0];
  const int* dsd2 = (const int*)d_in[1];
  const int* usu1 = (const int*)d_in[2];
  const int* label = (const int*)d_in[3];
  const float* symp = (const float*)d_in[4];
  const float* dise = (const float*)d_in[5];
  const float* Wu = (const float*)d_in[6];
  const float* W21 = (const float*)d_in[7];
  const float* W22 = (const float*)d_in[8];
  const float* W11 = (const float*)d_in[9];
  const float* W12 = (const float*)d_in[10];
  float* out = (float*)d_out;

  const int B = in_sizes[3];
  hipLaunchKernelGGL(hgnn_fused, dim3(B / 32), dim3(512), 0, stream,
                     dsd1, dsd2, usu1, label, symp, dise, W21, W22, W11, W12, Wu, out);
}